// Round 4
// baseline (136.600 us; speedup 1.0000x reference)
//
#include <hip/hip_runtime.h>
#include <math.h>

// Problem constants (match reference)
#define PH 256              // pano H
#define PW 512              // pano W
#define NRAYS (PH * PW)     // 131072
#define NS 300              // samples per ray
#define SEG 4               // segments per ray (= waves per block)
#define SEGLEN (NS / SEG)   // 75
#define NBLK (NRAYS / 64)   // 2048 blocks, 64 rays each
#define HV 256
#define WV 256
#define PI_F 3.14159265358979323846f

__device__ __forceinline__ float lerpf(float a, float b, float f) {
    return fmaf(f, b - a, a);
}

// Slow-path trilinear corner fetch from the (ground+voxel) volume, zero
// padding outside. Logical volume: D=65 slices; slice 0 is the constant
// ground plane (1000.0), slices 1..64 map to voxel[0..63].
__device__ __forceinline__ float fetch_vox(const float* __restrict__ vox,
                                           int iz, int iy, int ix) {
    bool valid = ((unsigned)ix < (unsigned)WV) &
                 ((unsigned)iy < (unsigned)HV) &
                 ((unsigned)iz < 65u);
    int czi = iz < 1 ? 1 : (iz > 64 ? 64 : iz);
    int cy = iy < 0 ? 0 : (iy > HV - 1 ? HV - 1 : iy);
    int cx = ix < 0 ? 0 : (ix > WV - 1 ? WV - 1 : ix);
    float v = vox[((czi - 1) << 16) + (cy << 8) + cx];
    if (iz == 0) v = 1000.0f;
    return valid ? v : 0.0f;
}

// Each block: 64 consecutive rays x 4 ray-segments (one segment per wave).
// Segments combine via the transmittance scan identity:
//   d = d0 + T0*d1 + T0*T1*d2 + T0*T1*T2*d3  (opacity likewise)
__global__ __launch_bounds__(256)
void render_seg_kernel(const float* __restrict__ vox,
                       float* __restrict__ out,       // [NRAYS] depth, [NRAYS..) opacity
                       float* __restrict__ blockMin,
                       float* __restrict__ blockMax) {
    const int t = threadIdx.x;
    const int lane = t & 63;
    const int s = t >> 6;               // segment / wave id, 0..3

    // interleave long (top-half, up-going) and short (bottom-half, ground)
    // ray groups across consecutive blocks so every CU gets a mix
    const int b = blockIdx.x;
    const int g = (b & 1) ? ((NBLK / 2) + (b >> 1)) : (b >> 1);
    const int r = g * 64 + lane;
    const int h = r >> 9;               // wave-uniform (64 lanes span w only)
    const int w = r & (PW - 1);

    // ray direction
    const float lat = (0.5f - (float)h * (1.0f / 255.0f)) * PI_F;
    const float lon = (-0.5f - 2.0f * (float)w * (1.0f / 511.0f)) * PI_F;
    float cl, sl, clon, slon;
    __sincosf(lat, &sl, &cl);
    __sincosf(lon, &slon, &clon);
    const float dx = cl * clon;
    const float dy = -cl * slon;
    const float dz = sl;
    const float oz = -1.0f + 2.0f * 2.0f / 128.0f;   // -0.96875

    // per-step deltas in voxel coords; sample i (global) sits at base + (i+1)*delta
    const float step = 1.0f / (float)NS;
    const float sxd = dx * 128.0f * step;
    const float syd = dy * 128.0f * step;
    const float szd = dz * 65.0f * step;
    const float intv = 64.0f / (float)NS;

    const int i0 = s * SEGLEN;

    float T = 1.0f;
    float depth = 0.0f;
    float opac = 0.0f;
    float dval = (float)i0 * intv;

    float xf = 127.5f + (float)i0 * sxd;
    float yf = 127.5f + (float)i0 * syd;
    float zf = (oz * 65.0f + 64.5f) + (float)i0 * szd;

    // segment dead-on-arrival check (first sample already outside, heading away)
    const float zf1 = zf + szd;
    const bool dead = ((zf1 < -1.0f) & (szd <= 0.0f)) | ((zf1 > 65.0f) & (szd >= 0.0f));

    if (!dead) {
        // cached 2x2x2 corners; reload only on cell change
        int px = -100000, py = -100000, pz = -100000;
        float c000 = 0.f, c001 = 0.f, c010 = 0.f, c011 = 0.f;
        float c100 = 0.f, c101 = 0.f, c110 = 0.f, c111 = 0.f;

        for (int i = 0; i < SEGLEN; ++i) {
            xf += sxd; yf += syd; zf += szd; dval += intv;

            float x0f = floorf(xf), y0f = floorf(yf), z0f = floorf(zf);
            float fx = xf - x0f, fy = yf - y0f, fz = zf - z0f;
            int x0 = (int)x0f, y0 = (int)y0f, z0 = (int)z0f;

            if ((x0 != px) | (y0 != py) | (z0 != pz)) {
                px = x0; py = y0; pz = z0;
                bool interior = ((unsigned)x0 < 255u) &
                                ((unsigned)y0 < 255u) &
                                ((unsigned)(z0 - 1) < 63u);
                if (interior) {
                    const float* p = vox + (((z0 - 1) << 16) + (y0 << 8) + x0);
                    c000 = p[0];       c001 = p[1];
                    c010 = p[256];     c011 = p[257];
                    c100 = p[65536];   c101 = p[65537];
                    c110 = p[65792];   c111 = p[65793];
                } else {
                    // trajectory early-out: fully outside, heading away
                    if (((pz < -1) & (szd <= 0.0f)) | ((pz > 64) & (szd >= 0.0f))) break;
                    c000 = fetch_vox(vox, z0,     y0,     x0);
                    c001 = fetch_vox(vox, z0,     y0,     x0 + 1);
                    c010 = fetch_vox(vox, z0,     y0 + 1, x0);
                    c011 = fetch_vox(vox, z0,     y0 + 1, x0 + 1);
                    c100 = fetch_vox(vox, z0 + 1, y0,     x0);
                    c101 = fetch_vox(vox, z0 + 1, y0,     x0 + 1);
                    c110 = fetch_vox(vox, z0 + 1, y0 + 1, x0);
                    c111 = fetch_vox(vox, z0 + 1, y0 + 1, x0 + 1);
                }
            }

            float l00 = lerpf(c000, c001, fx);
            float l01 = lerpf(c010, c011, fx);
            float l10 = lerpf(c100, c101, fx);
            float l11 = lerpf(c110, c111, fx);
            float lo  = lerpf(l00, l01, fy);
            float hi  = lerpf(l10, l11, fy);
            float sig = lerpf(lo, hi, fz);

            float e = __expf(-sig * intv);
            float prob = T - T * e;            // T * (1 - e)
            depth = fmaf(prob, dval, depth);
            opac += prob;
            T *= e;
            if (T < 1e-6f) break;              // local tail < 1e-6 relative
        }
    }

    // in-block segment combine through LDS
    __shared__ float sd[SEG][64];
    __shared__ float so[SEG][64];
    __shared__ float st[SEG][64];
    sd[s][lane] = depth;
    so[s][lane] = opac;
    st[s][lane] = T;
    __syncthreads();

    if (s == 0) {
        float d = sd[0][lane];
        float o = so[0][lane];
        float Tacc = st[0][lane];
        #pragma unroll
        for (int q = 1; q < SEG; ++q) {
            d = fmaf(Tacc, sd[q][lane], d);
            o = fmaf(Tacc, so[q][lane], o);
            Tacc *= st[q][lane];
        }
        out[r] = d;
        out[NRAYS + r] = o;

        // wave-wide min/max of depth (64 lanes)
        float mn = d, mx = d;
        #pragma unroll
        for (int off = 32; off > 0; off >>= 1) {
            mn = fminf(mn, __shfl_xor(mn, off));
            mx = fmaxf(mx, __shfl_xor(mx, off));
        }
        if (lane == 0) {
            blockMin[blockIdx.x] = mn;
            blockMax[blockIdx.x] = mx;
        }
    }
}

__global__ __launch_bounds__(256)
void reduce_minmax_kernel(const float* __restrict__ blockMin,
                          const float* __restrict__ blockMax,
                          float* __restrict__ mm) {
    __shared__ float smn[256];
    __shared__ float smx[256];
    const int t = threadIdx.x;
    float mn = 1e30f, mx = -1e30f;
    for (int i = t; i < NBLK; i += 256) {
        mn = fminf(mn, blockMin[i]);
        mx = fmaxf(mx, blockMax[i]);
    }
    smn[t] = mn;
    smx[t] = mx;
    __syncthreads();
    #pragma unroll
    for (int sft = 128; sft > 0; sft >>= 1) {
        if (t < sft) {
            smn[t] = fminf(smn[t], smn[t + sft]);
            smx[t] = fmaxf(smx[t], smx[t + sft]);
        }
        __syncthreads();
    }
    if (t == 0) {
        mm[0] = smn[0];
        mm[1] = smx[0];
    }
}

__global__ __launch_bounds__(256)
void normalize_kernel(float* __restrict__ out, const float* __restrict__ mm) {
    const int r = blockIdx.x * 256 + threadIdx.x;
    const float mn = mm[0];
    const float mx = mm[1];
    out[r] = (out[r] - mn) / (mx - mn);
}

extern "C" void kernel_launch(void* const* d_in, const int* in_sizes, int n_in,
                              void* d_out, int out_size, void* d_ws, size_t ws_size,
                              hipStream_t stream) {
    const float* vox = (const float*)d_in[0];
    float* out = (float*)d_out;
    float* wsf = (float*)d_ws;
    float* blockMin = wsf;              // NBLK
    float* blockMax = wsf + NBLK;       // NBLK
    float* mm = wsf + 2 * NBLK;         // 2

    render_seg_kernel<<<NBLK, 256, 0, stream>>>(vox, out, blockMin, blockMax);
    reduce_minmax_kernel<<<1, 256, 0, stream>>>(blockMin, blockMax, mm);
    normalize_kernel<<<NRAYS / 256, 256, 0, stream>>>(out, mm);
}

// Round 5
// 77.082 us; speedup vs baseline: 1.7721x; 1.7721x over previous
//
#include <hip/hip_runtime.h>
#include <hip/hip_fp16.h>
#include <math.h>

// Problem constants (match reference)
#define PH 256              // pano H
#define PW 512              // pano W
#define NRAYS (PH * PW)     // 131072
#define NS 300              // samples per ray
#define HV 256
#define WV 256
#define NB64 (NRAYS / 64)   // 2048 one-wave blocks
#define PI_F 3.14159265358979323846f

// packed volume: 65 slices (slice 0 = ground 1000), half2 x-pairs
#define PACK_ELEMS (65 * 256 * 256)
#define PACK_BYTES (PACK_ELEMS * 4)
#define WS_PACK_OFF 32768   // bytes; blockMin/blockMax/mm live below

__device__ __forceinline__ float lerpf(float a, float b, float f) {
    return fmaf(f, b - a, a);
}

// Slow-path trilinear corner fetch (f32 source), zero padding outside.
// Logical volume: D=65 slices; slice 0 = ground (1000.0), 1..64 = voxel[0..63].
__device__ __forceinline__ float fetch_vox(const float* __restrict__ vox,
                                           int iz, int iy, int ix) {
    bool valid = ((unsigned)ix < (unsigned)WV) &
                 ((unsigned)iy < (unsigned)HV) &
                 ((unsigned)iz < 65u);
    int czi = iz < 1 ? 1 : (iz > 64 ? 64 : iz);
    int cy = iy < 0 ? 0 : (iy > HV - 1 ? HV - 1 : iy);
    int cx = ix < 0 ? 0 : (ix > WV - 1 ? WV - 1 : ix);
    float v = vox[((czi - 1) << 16) + (cy << 8) + cx];
    if (iz == 0) v = 1000.0f;
    return valid ? v : 0.0f;
}

// Build P[iz][y][x] = half2(src(iz,y,x), src(iz,y,x+1)), iz in [0,64].
__global__ __launch_bounds__(256)
void pack_kernel(const float* __restrict__ vox, __half2* __restrict__ packed) {
    const int idx = blockIdx.x * 256 + threadIdx.x;   // 0 .. PACK_ELEMS-1
    const int iz = idx >> 16;
    const int rem = idx & 65535;
    const int x = rem & 255;
    float a, b;
    if (iz == 0) {
        a = 1000.0f; b = 1000.0f;
    } else {
        const float* row = vox + ((iz - 1) << 16) + (rem & ~255);
        a = row[x];
        b = row[x < 255 ? x + 1 : x];   // x=255 pair never read by fast path
    }
    packed[idx] = __floats2half2_rn(a, b);
}

// 1 thread per ray, 64-thread (one wave) blocks for fine-grain balance.
__global__ __launch_bounds__(64)
void render_packed_kernel(const __half2* __restrict__ packed,
                          const float* __restrict__ vox,
                          float* __restrict__ out,     // [NRAYS] depth, [NRAYS..) opacity
                          float* __restrict__ blockMin,
                          float* __restrict__ blockMax) {
    const int lane = threadIdx.x;
    const int r = blockIdx.x * 64 + lane;
    const int h = r >> 9;
    const int w = r & (PW - 1);

    const float lat = (0.5f - (float)h * (1.0f / 255.0f)) * PI_F;
    const float lon = (-0.5f - 2.0f * (float)w * (1.0f / 511.0f)) * PI_F;
    float cl, sl, clon, slon;
    __sincosf(lat, &sl, &cl);
    __sincosf(lon, &slon, &clon);
    const float dx = cl * clon;
    const float dy = -cl * slon;
    const float dz = sl;
    const float oz = -1.0f + 2.0f * 2.0f / 128.0f;   // -0.96875

    const float step = 1.0f / (float)NS;
    const float sxd = dx * 128.0f * step;
    const float syd = dy * 128.0f * step;
    const float szd = dz * 65.0f * step;
    const float intv = 64.0f / (float)NS;

    float T = 1.0f;
    float depth = 0.0f;
    float opac = 0.0f;
    float dval = 0.0f;

    float xf = 127.5f;
    float yf = 127.5f;
    float zf = oz * 65.0f + 64.5f;

    int px = -100000, py = -100000, pz = -100000;
    float c000 = 0.f, c001 = 0.f, c010 = 0.f, c011 = 0.f;
    float c100 = 0.f, c101 = 0.f, c110 = 0.f, c111 = 0.f;

    for (int i = 0; i < NS; ++i) {
        xf += sxd; yf += syd; zf += szd; dval += intv;

        float x0f = floorf(xf), y0f = floorf(yf), z0f = floorf(zf);
        float fx = xf - x0f, fy = yf - y0f, fz = zf - z0f;
        int x0 = (int)x0f, y0 = (int)y0f, z0 = (int)z0f;

        if ((x0 != px) | (y0 != py) | (z0 != pz)) {
            px = x0; py = y0; pz = z0;
            // ground slice (z0==0) is inside the fast path
            bool interior = ((unsigned)x0 < 255u) &
                            ((unsigned)y0 < 255u) &
                            ((unsigned)z0 < 64u);
            if (interior) {
                const __half2* p = packed + ((z0 << 16) + (y0 << 8) + x0);
                float2 a0 = __half22float2(p[0]);       // slice z0,   row y0
                float2 a1 = __half22float2(p[256]);     // slice z0,   row y0+1
                float2 b0 = __half22float2(p[65536]);   // slice z0+1, row y0
                float2 b1 = __half22float2(p[65792]);   // slice z0+1, row y0+1
                c000 = a0.x; c001 = a0.y;
                c010 = a1.x; c011 = a1.y;
                c100 = b0.x; c101 = b0.y;
                c110 = b1.x; c111 = b1.y;
            } else {
                // trajectory early-outs: fully outside and heading away
                if ((((z0 < -1) & (szd <= 0.0f)) | ((z0 > 64) & (szd >= 0.0f))) |
                    (((x0 < -1) & (sxd <= 0.0f)) | ((x0 > 255) & (sxd >= 0.0f))) |
                    (((y0 < -1) & (syd <= 0.0f)) | ((y0 > 255) & (syd >= 0.0f)))) break;
                c000 = fetch_vox(vox, z0,     y0,     x0);
                c001 = fetch_vox(vox, z0,     y0,     x0 + 1);
                c010 = fetch_vox(vox, z0,     y0 + 1, x0);
                c011 = fetch_vox(vox, z0,     y0 + 1, x0 + 1);
                c100 = fetch_vox(vox, z0 + 1, y0,     x0);
                c101 = fetch_vox(vox, z0 + 1, y0,     x0 + 1);
                c110 = fetch_vox(vox, z0 + 1, y0 + 1, x0);
                c111 = fetch_vox(vox, z0 + 1, y0 + 1, x0 + 1);
            }
        }

        float l00 = lerpf(c000, c001, fx);
        float l01 = lerpf(c010, c011, fx);
        float l10 = lerpf(c100, c101, fx);
        float l11 = lerpf(c110, c111, fx);
        float lo  = lerpf(l00, l01, fy);
        float hi  = lerpf(l10, l11, fy);
        float sig = lerpf(lo, hi, fz);

        float e = __expf(-sig * intv);
        float prob = T - T * e;            // T * (1 - e)
        depth = fmaf(prob, dval, depth);
        opac += prob;
        T *= e;
        if (T < 1e-6f) break;
    }

    out[r] = depth;
    out[NRAYS + r] = opac;

    // wave min/max of depth
    float mn = depth, mx = depth;
    #pragma unroll
    for (int off = 32; off > 0; off >>= 1) {
        mn = fminf(mn, __shfl_xor(mn, off));
        mx = fmaxf(mx, __shfl_xor(mx, off));
    }
    if (lane == 0) {
        blockMin[blockIdx.x] = mn;
        blockMax[blockIdx.x] = mx;
    }
}

// f32 fallback (no packed scratch): identical structure, 8 scalar loads.
__global__ __launch_bounds__(64)
void render_f32_kernel(const float* __restrict__ vox,
                       float* __restrict__ out,
                       float* __restrict__ blockMin,
                       float* __restrict__ blockMax) {
    const int lane = threadIdx.x;
    const int r = blockIdx.x * 64 + lane;
    const int h = r >> 9;
    const int w = r & (PW - 1);

    const float lat = (0.5f - (float)h * (1.0f / 255.0f)) * PI_F;
    const float lon = (-0.5f - 2.0f * (float)w * (1.0f / 511.0f)) * PI_F;
    float cl, sl, clon, slon;
    __sincosf(lat, &sl, &cl);
    __sincosf(lon, &slon, &clon);
    const float dx = cl * clon;
    const float dy = -cl * slon;
    const float dz = sl;
    const float oz = -0.96875f;

    const float step = 1.0f / (float)NS;
    const float sxd = dx * 128.0f * step;
    const float syd = dy * 128.0f * step;
    const float szd = dz * 65.0f * step;
    const float intv = 64.0f / (float)NS;

    float T = 1.0f, depth = 0.0f, opac = 0.0f, dval = 0.0f;
    float xf = 127.5f, yf = 127.5f, zf = oz * 65.0f + 64.5f;

    int px = -100000, py = -100000, pz = -100000;
    float c000 = 0.f, c001 = 0.f, c010 = 0.f, c011 = 0.f;
    float c100 = 0.f, c101 = 0.f, c110 = 0.f, c111 = 0.f;

    for (int i = 0; i < NS; ++i) {
        xf += sxd; yf += syd; zf += szd; dval += intv;
        float x0f = floorf(xf), y0f = floorf(yf), z0f = floorf(zf);
        float fx = xf - x0f, fy = yf - y0f, fz = zf - z0f;
        int x0 = (int)x0f, y0 = (int)y0f, z0 = (int)z0f;

        if ((x0 != px) | (y0 != py) | (z0 != pz)) {
            px = x0; py = y0; pz = z0;
            bool interior = ((unsigned)x0 < 255u) &
                            ((unsigned)y0 < 255u) &
                            ((unsigned)(z0 - 1) < 63u);
            if (interior) {
                const float* p = vox + (((z0 - 1) << 16) + (y0 << 8) + x0);
                c000 = p[0];     c001 = p[1];
                c010 = p[256];   c011 = p[257];
                c100 = p[65536]; c101 = p[65537];
                c110 = p[65792]; c111 = p[65793];
            } else {
                if ((((z0 < -1) & (szd <= 0.0f)) | ((z0 > 64) & (szd >= 0.0f))) |
                    (((x0 < -1) & (sxd <= 0.0f)) | ((x0 > 255) & (sxd >= 0.0f))) |
                    (((y0 < -1) & (syd <= 0.0f)) | ((y0 > 255) & (syd >= 0.0f)))) break;
                c000 = fetch_vox(vox, z0,     y0,     x0);
                c001 = fetch_vox(vox, z0,     y0,     x0 + 1);
                c010 = fetch_vox(vox, z0,     y0 + 1, x0);
                c011 = fetch_vox(vox, z0,     y0 + 1, x0 + 1);
                c100 = fetch_vox(vox, z0 + 1, y0,     x0);
                c101 = fetch_vox(vox, z0 + 1, y0,     x0 + 1);
                c110 = fetch_vox(vox, z0 + 1, y0 + 1, x0);
                c111 = fetch_vox(vox, z0 + 1, y0 + 1, x0 + 1);
            }
        }

        float l00 = lerpf(c000, c001, fx);
        float l01 = lerpf(c010, c011, fx);
        float l10 = lerpf(c100, c101, fx);
        float l11 = lerpf(c110, c111, fx);
        float lo  = lerpf(l00, l01, fy);
        float hi  = lerpf(l10, l11, fy);
        float sig = lerpf(lo, hi, fz);

        float e = __expf(-sig * intv);
        float prob = T - T * e;
        depth = fmaf(prob, dval, depth);
        opac += prob;
        T *= e;
        if (T < 1e-6f) break;
    }

    out[r] = depth;
    out[NRAYS + r] = opac;

    float mn = depth, mx = depth;
    #pragma unroll
    for (int off = 32; off > 0; off >>= 1) {
        mn = fminf(mn, __shfl_xor(mn, off));
        mx = fmaxf(mx, __shfl_xor(mx, off));
    }
    if (lane == 0) {
        blockMin[blockIdx.x] = mn;
        blockMax[blockIdx.x] = mx;
    }
}

__global__ __launch_bounds__(256)
void reduce_minmax_kernel(const float* __restrict__ blockMin,
                          const float* __restrict__ blockMax,
                          float* __restrict__ mm) {
    __shared__ float smn[256];
    __shared__ float smx[256];
    const int t = threadIdx.x;
    float mn = 1e30f, mx = -1e30f;
    for (int i = t; i < NB64; i += 256) {
        mn = fminf(mn, blockMin[i]);
        mx = fmaxf(mx, blockMax[i]);
    }
    smn[t] = mn;
    smx[t] = mx;
    __syncthreads();
    #pragma unroll
    for (int sft = 128; sft > 0; sft >>= 1) {
        if (t < sft) {
            smn[t] = fminf(smn[t], smn[t + sft]);
            smx[t] = fmaxf(smx[t], smx[t + sft]);
        }
        __syncthreads();
    }
    if (t == 0) {
        mm[0] = smn[0];
        mm[1] = smx[0];
    }
}

__global__ __launch_bounds__(256)
void normalize_kernel(float* __restrict__ out, const float* __restrict__ mm) {
    const int r = blockIdx.x * 256 + threadIdx.x;
    const float mn = mm[0];
    const float mx = mm[1];
    out[r] = (out[r] - mn) / (mx - mn);
}

extern "C" void kernel_launch(void* const* d_in, const int* in_sizes, int n_in,
                              void* d_out, int out_size, void* d_ws, size_t ws_size,
                              hipStream_t stream) {
    const float* vox = (const float*)d_in[0];
    float* out = (float*)d_out;
    char* ws = (char*)d_ws;
    float* blockMin = (float*)ws;                     // NB64 floats @ 0
    float* blockMax = (float*)(ws + 8192);            // NB64 floats
    float* mm       = (float*)(ws + 16384);           // 2 floats

    if (ws_size >= (size_t)WS_PACK_OFF + (size_t)PACK_BYTES) {
        __half2* packed = (__half2*)(ws + WS_PACK_OFF);
        pack_kernel<<<PACK_ELEMS / 256, 256, 0, stream>>>(vox, packed);
        render_packed_kernel<<<NB64, 64, 0, stream>>>(packed, vox, out, blockMin, blockMax);
    } else {
        render_f32_kernel<<<NB64, 64, 0, stream>>>(vox, out, blockMin, blockMax);
    }
    reduce_minmax_kernel<<<1, 256, 0, stream>>>(blockMin, blockMax, mm);
    normalize_kernel<<<NRAYS / 256, 256, 0, stream>>>(out, mm);
}

// Round 6
// 50.064 us; speedup vs baseline: 2.7285x; 1.5397x over previous
//
#include <hip/hip_runtime.h>
#include <hip/hip_fp16.h>
#include <math.h>

// Problem constants (match reference)
#define PH 256
#define PW 512
#define NRAYS (PH * PW)     // 131072
#define NS 300
#define NB64 (NRAYS / 64)   // 2048 one-wave blocks
#define PI_F 3.14159265358979323846f

// Padded volume: P[zp][yp][xp], zp in [0,66], yp/xp in [0,257].
// Logical (zz,y,x) = (zp-1, yp-1, xp-1); zz=0 -> ground 1000, zz in [1,64] ->
// voxel[zz-1], everything else (pads) = 0. Zero padding == reference's
// out-of-range gather = 0, so the render loop needs NO bounds logic at all.
#define XS 258
#define SS (258 * 258)          // 66564
#define ZSL 67
#define PVOX_ELEMS (ZSL * SS)   // 4,459,788
#define WS_VOL_OFF 32768

__device__ __forceinline__ float lerpf(float a, float b, float f) {
    return fmaf(f, b - a, a);
}

template <bool HALF>
__global__ __launch_bounds__(256)
void pack_kernel(const float* __restrict__ vox, void* __restrict__ pv) {
    const int idx = blockIdx.x * 256 + threadIdx.x;
    if (idx >= PVOX_ELEMS) return;
    const int zp = idx / SS;
    const int rem = idx - zp * SS;
    const int yp = rem / XS;
    const int xp = rem - yp * XS;
    const int x = xp - 1, y = yp - 1, zz = zp - 1;
    float v = 0.0f;
    if (((unsigned)x < 256u) & ((unsigned)y < 256u)) {
        if (zz == 0) v = 1000.0f;
        else if ((unsigned)(zz - 1) < 64u) v = vox[((zz - 1) << 16) + (y << 8) + x];
    }
    if (HALF) ((__half*)pv)[idx] = __float2half_rn(v);
    else      ((float*)pv)[idx] = v;
}

template <bool HALF>
__device__ __forceinline__ float sample_sigma(const void* __restrict__ pvv,
                                              float fs, float sxd, float syd, float szd) {
    const float xf = fmaf(fs, sxd, 127.5f);
    const float yf = fmaf(fs, syd, 127.5f);
    const float zf = fmaf(fs, szd, 1.53125f);
    const float xw = floorf(xf), yw = floorf(yf), zw = floorf(zf);
    const float fx = xf - xw, fy = yf - yw, fz = zf - zw;
    const int x0 = (int)xw, y0 = (int)yw, z0 = (int)zw;
    const int off = z0 * SS + y0 * XS + x0 + (SS + XS + 1);   // +1 pad shift each axis
    float c000, c001, c010, c011, c100, c101, c110, c111;
    if (HALF) {
        const __half* p = (const __half*)pvv + off;
        c000 = __half2float(p[0]);       c001 = __half2float(p[1]);
        c010 = __half2float(p[XS]);      c011 = __half2float(p[XS + 1]);
        c100 = __half2float(p[SS]);      c101 = __half2float(p[SS + 1]);
        c110 = __half2float(p[SS + XS]); c111 = __half2float(p[SS + XS + 1]);
    } else {
        const float* p = (const float*)pvv + off;
        c000 = p[0];       c001 = p[1];
        c010 = p[XS];      c011 = p[XS + 1];
        c100 = p[SS];      c101 = p[SS + 1];
        c110 = p[SS + XS]; c111 = p[SS + XS + 1];
    }
    const float l00 = lerpf(c000, c001, fx);
    const float l01 = lerpf(c010, c011, fx);
    const float l10 = lerpf(c100, c101, fx);
    const float l11 = lerpf(c110, c111, fx);
    return lerpf(lerpf(l00, l01, fy), lerpf(l10, l11, fy), fz);
}

template <bool HALF>
__global__ __launch_bounds__(64)
void render_kernel(const void* __restrict__ pvv,
                   float* __restrict__ out,
                   float* __restrict__ bmin, float* __restrict__ bmax) {
    const int lane = threadIdx.x;
    const int r = blockIdx.x * 64 + lane;
    const int h = r >> 9;
    const int w = r & (PW - 1);

    const float lat = (0.5f - (float)h * (1.0f / 255.0f)) * PI_F;
    const float lon = (-0.5f - 2.0f * (float)w * (1.0f / 511.0f)) * PI_F;
    float cl, sl, clon, slon;
    __sincosf(lat, &sl, &cl);
    __sincosf(lon, &slon, &clon);
    const float sxd = cl * clon * (128.0f / NS);
    const float syd = -cl * slon * (128.0f / NS);
    const float szd = sl * (65.0f / NS);
    const float intv = 64.0f / (float)NS;

    // Ray-box clip: samples with pos outside box have exactly sigma=0 (pads),
    // and the box is convex so once out, always out. Samples s=1..nrun valid.
    const float m = 1e-3f;
    float nx = 1e9f, ny = 1e9f, nz = 1e9f;
    if (sxd >  1e-8f) nx = (256.0f - m - 127.5f) / sxd;
    if (sxd < -1e-8f) nx = (127.5f - (-1.0f + m)) / (-sxd);
    if (syd >  1e-8f) ny = (256.0f - m - 127.5f) / syd;
    if (syd < -1e-8f) ny = (127.5f - (-1.0f + m)) / (-syd);
    if (szd >  1e-8f) nz = (65.0f - m - 1.53125f) / szd;
    if (szd < -1e-8f) nz = (1.53125f - (-1.0f + m)) / (-szd);
    const float nmin = fminf(fminf(nx, ny), nz);
    int nrun = NS;
    if (nmin < (float)NS) nrun = (int)nmin;
    if (nrun < 0) nrun = 0;

    float T = 1.0f, depth = 0.0f, opac = 0.0f, dval = 0.0f;

    int i = 0;
    for (; i + 4 <= nrun; i += 4) {
        float sg[4];
        const float fb = (float)i;
        #pragma unroll
        for (int j = 0; j < 4; ++j)
            sg[j] = sample_sigma<HALF>(pvv, fb + (float)(j + 1), sxd, syd, szd);
        #pragma unroll
        for (int j = 0; j < 4; ++j) {
            const float e = __expf(-sg[j] * intv);
            const float prob = fmaf(-T, e, T);     // T*(1-e)
            dval += intv;
            depth = fmaf(prob, dval, depth);
            opac += prob;
            T *= e;
        }
        if (T < 1e-6f) break;
    }
    if (T >= 1e-6f) {
        for (; i < nrun; ++i) {
            const float sg = sample_sigma<HALF>(pvv, (float)(i + 1), sxd, syd, szd);
            const float e = __expf(-sg * intv);
            const float prob = fmaf(-T, e, T);
            dval += intv;
            depth = fmaf(prob, dval, depth);
            opac += prob;
            T *= e;
            if (T < 1e-6f) break;
        }
    }

    out[r] = depth;
    out[NRAYS + r] = opac;

    // wave min/max of depth
    float mn = depth, mx = depth;
    #pragma unroll
    for (int off = 32; off > 0; off >>= 1) {
        mn = fminf(mn, __shfl_xor(mn, off));
        mx = fmaxf(mx, __shfl_xor(mx, off));
    }
    if (lane == 0) {
        bmin[blockIdx.x] = mn;
        bmax[blockIdx.x] = mx;
    }
}

__global__ __launch_bounds__(256)
void reduce_minmax_kernel(const float* __restrict__ blockMin,
                          const float* __restrict__ blockMax,
                          float* __restrict__ mm) {
    __shared__ float smn[256];
    __shared__ float smx[256];
    const int t = threadIdx.x;
    float mn = 1e30f, mx = -1e30f;
    for (int i = t; i < NB64; i += 256) {
        mn = fminf(mn, blockMin[i]);
        mx = fmaxf(mx, blockMax[i]);
    }
    smn[t] = mn;
    smx[t] = mx;
    __syncthreads();
    #pragma unroll
    for (int sft = 128; sft > 0; sft >>= 1) {
        if (t < sft) {
            smn[t] = fminf(smn[t], smn[t + sft]);
            smx[t] = fmaxf(smx[t], smx[t + sft]);
        }
        __syncthreads();
    }
    if (t == 0) {
        mm[0] = smn[0];
        mm[1] = smx[0];
    }
}

__global__ __launch_bounds__(256)
void normalize_kernel(float* __restrict__ out, const float* __restrict__ mm) {
    const int r = blockIdx.x * 256 + threadIdx.x;
    const float mn = mm[0];
    const float mx = mm[1];
    out[r] = (out[r] - mn) / (mx - mn);
}

extern "C" void kernel_launch(void* const* d_in, const int* in_sizes, int n_in,
                              void* d_out, int out_size, void* d_ws, size_t ws_size,
                              hipStream_t stream) {
    const float* vox = (const float*)d_in[0];
    float* out = (float*)d_out;
    char* ws = (char*)d_ws;
    float* bmin = (float*)ws;               // 2048 floats
    float* bmax = (float*)(ws + 8192);      // 2048 floats
    float* mm   = (float*)(ws + 16384);     // 2 floats
    void* pv = (void*)(ws + WS_VOL_OFF);

    const int pblocks = (PVOX_ELEMS + 255) / 256;
    if (ws_size >= (size_t)WS_VOL_OFF + (size_t)PVOX_ELEMS * sizeof(float)) {
        pack_kernel<false><<<pblocks, 256, 0, stream>>>(vox, pv);
        render_kernel<false><<<NB64, 64, 0, stream>>>(pv, out, bmin, bmax);
    } else {
        pack_kernel<true><<<pblocks, 256, 0, stream>>>(vox, pv);
        render_kernel<true><<<NB64, 64, 0, stream>>>(pv, out, bmin, bmax);
    }
    reduce_minmax_kernel<<<1, 256, 0, stream>>>(bmin, bmax, mm);
    normalize_kernel<<<NRAYS / 256, 256, 0, stream>>>(out, mm);
}